// Round 8
// baseline (163.879 us; speedup 1.0000x reference)
//
#include <hip/hip_runtime.h>
#include <hip/hip_bf16.h>

// ---- problem constants ----
constexpr int BATCH = 256;          // B
constexpr int MTOK  = 128;          // tokens per text
constexpr int DDIM  = 768;          // embedding dim
constexpr int NV    = BATCH * DDIM; // v elems (= Vq elems)
constexpr float INV_TEMP = 1.0f / 0.07f;

typedef __bf16 bf16;
typedef __bf16 bf16x8 __attribute__((ext_vector_type(8)));
typedef float  f32x4  __attribute__((ext_vector_type(4)));

// ============================================================
// Kernel 0: pack V fp32 -> bf16 in MFMA A-fragment layout; zero out[0].
// Vq chunk c = (g*24 + ks)*64 + lane ; lane chunk = 8 bf16 covering
// rows g*16+l15, k = ks*32 + quad*8.. +8.  One frag = 1 KB contiguous.
// ============================================================
__global__ __launch_bounds__(256) void pack_v_kernel(
        const float* __restrict__ V, bf16x8* __restrict__ Vq,
        float* __restrict__ out) {
    if (blockIdx.x == 0 && threadIdx.x == 0) out[0] = 0.f;  // for ce atomics
    int c = blockIdx.x * 256 + threadIdx.x;        // 24576 chunks
    int lane = c & 63, fs = c >> 6;
    int ks = fs % 24, g = fs / 24;
    int l15 = lane & 15, quad = lane >> 4;
    const float* src = V + (size_t)(g * 16 + l15) * DDIM + ks * 32 + quad * 8;
    float4 f0 = *(const float4*)(src);
    float4 f1 = *(const float4*)(src + 4);
    bf16x8 o;
    o[0] = (bf16)f0.x; o[1] = (bf16)f0.y; o[2] = (bf16)f0.z; o[3] = (bf16)f0.w;
    o[4] = (bf16)f1.x; o[5] = (bf16)f1.y; o[6] = (bf16)f1.z; o[7] = (bf16)f1.w;
    Vq[c] = o;
}

// ============================================================
// Kernel 1 (v8): block (j, nh) -> M=256 x N=64 tokens, BK=64, 12 slabs.
// A: direct coalesced frag loads from L2-resident Vq, depth-2 prefetch.
// B: fp32 -> regs -> bf16 -> LDS, FOUR rotating buffers, ONE barrier
//    per PAIR of slabs (6 barriers total vs 12 in v7).
// Grid 512, 256 thr -> 2 blocks/CU.
// ============================================================
__global__ __launch_bounds__(256, 2) void gemm_max_kernel(
        const bf16*  __restrict__ Vq,  // packed A frags
        const float* __restrict__ T,   // [32768][768] fp32
        float* __restrict__ Sp) {      // [2][256][256]  Sp[nh][j][i]
    // 4 bufs x (2 khalf x 64 rows x 64 B) = 4 x 8192
    __shared__ char  ldsB[4 * 8192];
    __shared__ float smax[256];

    const int jt   = blockIdx.x >> 1;   // text j
    const int nh   = blockIdx.x & 1;    // token half (64 tokens)
    const int tid  = threadIdx.x;
    const int w    = tid >> 6;          // wave 0..3 -> M stripe of 64
    const int lane = tid & 63;
    const int quad = lane >> 4;
    const int l15  = lane & 15;

    // --- A frag bases: m-tile t -> 16-row tile g = w*4+t ---
    const bf16* aBase[4];
#pragma unroll
    for (int t = 0; t < 4; ++t)
        aBase[t] = Vq + ((size_t)(w * 4 + t) * 24) * 512 + lane * 8;

    // --- B staging: chunk c = q*256+tid -> row = c>>3 (0..63), kp = c&7 ---
    const float* gB[2];
    int bwoff[2];
#pragma unroll
    for (int q = 0; q < 2; ++q) {
        int c = q * 256 + tid;
        int row = c >> 3, kp = c & 7;
        gB[q] = T + (size_t)(jt * MTOK + nh * 64 + row) * DDIM + kp * 8;
        bwoff[q] = (kp >> 2) * 4096 + row * 64 + ((kp & 3) << 4);
    }

    // --- B frag read offsets (khalf/buf terms added in loop) ---
    int boff[4];
#pragma unroll
    for (int tc = 0; tc < 4; ++tc)
        boff[tc] = (tc * 16 + l15) * 64 + quad * 16;

    f32x4 acc[4][4] = {};

    auto cvt_store = [&](const float4* r, int q, int bufo) {
        bf16x8 o;
        o[0] = (bf16)r[0].x; o[1] = (bf16)r[0].y; o[2] = (bf16)r[0].z; o[3] = (bf16)r[0].w;
        o[4] = (bf16)r[1].x; o[5] = (bf16)r[1].y; o[6] = (bf16)r[1].z; o[7] = (bf16)r[1].w;
        *(bf16x8*)(ldsB + bufo + bwoff[q]) = o;
    };

    // breg[sp][q][half] : two slabs in flight
    float4 breg[2][2][2];

    // prologue: slabs 0,1 -> LDS bufs 0,1 ; slabs 2,3 -> regs ; A hs=0,1 -> regs
#pragma unroll
    for (int sp = 0; sp < 2; ++sp)
#pragma unroll
        for (int q = 0; q < 2; ++q) {
            float4 r[2];
            r[0] = *(const float4*)(gB[q] + sp * 64);
            r[1] = *(const float4*)(gB[q] + sp * 64 + 4);
            cvt_store(r, q, sp * 8192);
            breg[sp][q][0] = *(const float4*)(gB[q] + (sp + 2) * 64);
            breg[sp][q][1] = *(const float4*)(gB[q] + (sp + 2) * 64 + 4);
        }
    bf16x8 apre[2][4];
#pragma unroll
    for (int h = 0; h < 2; ++h)
#pragma unroll
        for (int t = 0; t < 4; ++t)
            apre[h][t] = *(const bf16x8*)(aBase[t] + (size_t)h * 512);
    __syncthreads();

    // 6 pairs of slabs (12 slabs of BK=64; 24 h-steps of K=32)
    for (int p = 0; p < 6; ++p) {
        if (p < 5) {   // store slabs 2p+2, 2p+3 (in regs) -> their bufs
#pragma unroll
            for (int sp = 0; sp < 2; ++sp)
#pragma unroll
                for (int q = 0; q < 2; ++q)
                    cvt_store(breg[sp][q], q, ((2 * p + 2 + sp) & 3) * 8192);
        }
        if (p < 4) {   // fetch slabs 2p+4, 2p+5 -> regs
#pragma unroll
            for (int sp = 0; sp < 2; ++sp)
#pragma unroll
                for (int q = 0; q < 2; ++q) {
                    const float* ptr = gB[q] + (2 * p + 4 + sp) * 64;
                    breg[sp][q][0] = *(const float4*)(ptr);
                    breg[sp][q][1] = *(const float4*)(ptr + 4);
                }
        }
#pragma unroll
        for (int hh = 0; hh < 4; ++hh) {
            const int hs   = p * 4 + hh;        // global h-step 0..23
            const int slab = hs >> 1;
            const int bbase = (slab & 3) * 8192 + (hs & 1) * 4096;
            bf16x8 af[4], bb[4];
#pragma unroll
            for (int t = 0; t < 4; ++t) af[t] = apre[hh & 1][t];
            if (hs + 2 < 24) {                  // depth-2 A prefetch
#pragma unroll
                for (int t = 0; t < 4; ++t)
                    apre[hh & 1][t] = *(const bf16x8*)(aBase[t] + (size_t)(hs + 2) * 512);
            }
#pragma unroll
            for (int tc = 0; tc < 4; ++tc)
                bb[tc] = *(const bf16x8*)(ldsB + bbase + boff[tc]);
#pragma unroll
            for (int tr = 0; tr < 4; ++tr)
#pragma unroll
                for (int tc = 0; tc < 4; ++tc)
                    acc[tr][tc] = __builtin_amdgcn_mfma_f32_16x16x32_bf16(
                        af[tr], bb[tc], acc[tr][tc], 0, 0, 0);
        }
        if (p < 5) __syncthreads();  // pair p reads done; pair p stores visible
    }

    // epilogue: max over this half's 64 tokens (cols = tc*16 + l15)
    // C/D layout: col = lane&15, row = quad*4 + reg   [m89/m91]
#pragma unroll
    for (int tr = 0; tr < 4; ++tr) {
#pragma unroll
        for (int r = 0; r < 4; ++r) {
            float v = fmaxf(fmaxf(acc[tr][0][r], acc[tr][1][r]),
                            fmaxf(acc[tr][2][r], acc[tr][3][r]));
            v = fmaxf(v, __shfl_xor(v, 1, 64));
            v = fmaxf(v, __shfl_xor(v, 2, 64));
            v = fmaxf(v, __shfl_xor(v, 4, 64));
            v = fmaxf(v, __shfl_xor(v, 8, 64));
            if (l15 == 0)
                smax[w * 64 + tr * 16 + quad * 4 + r] = v;
        }
    }
    __syncthreads();
    Sp[((size_t)nh * BATCH + jt) * BATCH + tid] = smax[tid] * INV_TEMP;
}

// ============================================================
// CE: block t computes 0.5*(lse_j S[t][j] + lse_i S[i][t]) - S[t][t],
// atomically accumulates term/256 into out[0] (zeroed by pack_v).
// S[i][j] = max(Sp[0][j][i], Sp[1][j][i]); all reads coalesced.
// ============================================================
__global__ __launch_bounds__(64) void ce_kernel(
        const float* __restrict__ Sp, float* __restrict__ out) {
    const int t = blockIdx.x;
    const int l = threadIdx.x;
    const float* Sp0 = Sp;
    const float* Sp1 = Sp + BATCH * BATCH;

    float vr[4], vc[4];
#pragma unroll
    for (int p = 0; p < 4; ++p) {
        int j = p * 64 + l;
        vr[p] = fmaxf(Sp0[j * BATCH + t], Sp1[j * BATCH + t]);  // S[t][j]
        int i = p * 64 + l;
        vc[p] = fmaxf(Sp0[t * BATCH + i], Sp1[t * BATCH + i]);  // S[i][t]
    }
    float mr = fmaxf(fmaxf(vr[0], vr[1]), fmaxf(vr[2], vr[3]));
    float mc = fmaxf(fmaxf(vc[0], vc[1]), fmaxf(vc[2], vc[3]));
    for (int o = 32; o > 0; o >>= 1) {
        mr = fmaxf(mr, __shfl_xor(mr, o, 64));
        mc = fmaxf(mc, __shfl_xor(mc, o, 64));
    }
    float sr = 0.f, sc = 0.f;
#pragma unroll
    for (int p = 0; p < 4; ++p) {
        sr += expf(vr[p] - mr);
        sc += expf(vc[p] - mc);
    }
    for (int o = 32; o > 0; o >>= 1) {
        sr += __shfl_xor(sr, o, 64);
        sc += __shfl_xor(sc, o, 64);
    }
    if (l == 0) {
        float diag = fmaxf(Sp0[t * BATCH + t], Sp1[t * BATCH + t]);
        float term = 0.5f * ((mr + logf(sr)) + (mc + logf(sc))) - diag;
        atomicAdd(out, term * (1.0f / (float)BATCH));
    }
}

// ============================================================
extern "C" void kernel_launch(void* const* d_in, const int* in_sizes, int n_in,
                              void* d_out, int out_size, void* d_ws, size_t ws_size,
                              hipStream_t stream) {
    const float* v = (const float*)d_in[0];   // [256][768] fp32
    const float* T = (const float*)d_in[1];   // [256][128][768] fp32

    // ws: [ Vq bf16 NV | Sp f32 2*256*256 ]
    bf16*  Vq = (bf16*)d_ws;
    float* Sp = (float*)((char*)d_ws + (size_t)NV * sizeof(bf16));

    pack_v_kernel<<<96, 256, 0, stream>>>(v, (bf16x8*)Vq, (float*)d_out);
    gemm_max_kernel<<<512, 256, 0, stream>>>(Vq, T, Sp);
    ce_kernel<<<256, 64, 0, stream>>>(Sp, (float*)d_out);
}